// Round 6
// baseline (453.303 us; speedup 1.0000x reference)
//
#include <hip/hip_runtime.h>
#include <hip/hip_fp16.h>

#define NEG_SLOPE 0.2f
#define FINF __builtin_inff()

// ================= prologue kernels (once per call) =================

__global__ __launch_bounds__(256) void k_deg(const int* __restrict__ dst,
                                             int* __restrict__ deg, int ne) {
    int e = blockIdx.x * blockDim.x + threadIdx.x;
    if (e < ne) atomicAdd(&deg[dst[e]], 1);
}

__global__ __launch_bounds__(1024) void k_scan(const int* __restrict__ deg,
                                               int* __restrict__ rowptr,
                                               int* __restrict__ cursor, int n) {
    __shared__ int wsum[16];
    __shared__ int carry_s;
    int t = threadIdx.x, lane = t & 63, w = t >> 6;
    if (t == 0) carry_s = 0;
    __syncthreads();
    for (int base = 0; base < n; base += 4096) {
        int i0 = base + t * 4;
        int4 v;
        v.x = (i0 + 0 < n) ? deg[i0 + 0] : 0;
        v.y = (i0 + 1 < n) ? deg[i0 + 1] : 0;
        v.z = (i0 + 2 < n) ? deg[i0 + 2] : 0;
        v.w = (i0 + 3 < n) ? deg[i0 + 3] : 0;
        int tsum = v.x + v.y + v.z + v.w;
        int s = tsum;
        #pragma unroll
        for (int off = 1; off < 64; off <<= 1) {
            int y = __shfl_up(s, off);
            if (lane >= off) s += y;
        }
        if (lane == 63) wsum[w] = s;
        __syncthreads();
        if (w == 0 && lane < 16) {
            int ws = wsum[lane];
            #pragma unroll
            for (int off = 1; off < 16; off <<= 1) {
                int y = __shfl_up(ws, off);
                if (lane >= off) ws += y;
            }
            wsum[lane] = ws;
        }
        __syncthreads();
        int carry = carry_s;
        int wexcl = (w > 0) ? wsum[w - 1] : 0;
        int excl = carry + wexcl + (s - tsum);
        int e0 = excl;
        int e1 = e0 + v.x;
        int e2 = e1 + v.y;
        int e3 = e2 + v.z;
        if (i0 + 0 < n) { rowptr[i0 + 0] = e0; cursor[i0 + 0] = e0; }
        if (i0 + 1 < n) { rowptr[i0 + 1] = e1; cursor[i0 + 1] = e1; }
        if (i0 + 2 < n) { rowptr[i0 + 2] = e2; cursor[i0 + 2] = e2; }
        if (i0 + 3 < n) { rowptr[i0 + 3] = e3; cursor[i0 + 3] = e3; }
        __syncthreads();
        if (t == 0) carry_s = carry + wsum[15];
        __syncthreads();
    }
    if (t == 0) rowptr[n] = carry_s;
}

__global__ __launch_bounds__(256) void k_scatter(const int* __restrict__ src,
                                                 const int* __restrict__ dst,
                                                 int* __restrict__ cursor,
                                                 int* __restrict__ csr_src, int ne) {
    int e = blockIdx.x * blockDim.x + threadIdx.x;
    if (e >= ne) return;
    int pos = atomicAdd(&cursor[dst[e]], 1);
    csr_src[pos] = src[e];
}

// W[l][k][h*64+f] -> Wt[l][k][f*4+h]   (all 4 layers)
__global__ __launch_bounds__(256) void k_transW(const float* __restrict__ W,
                                                float* __restrict__ Wt) {
    int i = blockIdx.x * blockDim.x + threadIdx.x;
    if (i >= 4 * 64 * 256) return;
    int l = i >> 14, r = i & 16383;
    int k = r >> 8, c = r & 255;
    int f = c >> 2, h = c & 3;
    Wt[i] = W[(l << 14) + (k << 8) + h * 64 + f];
}

// WAB[l][k][j]: j<4 -> sum_f W[l][k][j*64+f]*al[l][j][f]; j>=4 -> ar (head j-4)
// bsum[l][f] = sum_h bias[l][h][f]
__global__ __launch_bounds__(256) void k_prep(const float* __restrict__ W,
                                              const float* __restrict__ al,
                                              const float* __restrict__ ar,
                                              const float* __restrict__ bias,
                                              float* __restrict__ WAB,
                                              float* __restrict__ bsum) {
    int i = blockIdx.x * blockDim.x + threadIdx.x;
    if (i < 4 * 64 * 8) {
        int l = i >> 9, r = i & 511;
        int k = r >> 3, j = r & 7;
        int hh = j & 3;
        const float* wrow = W + (l << 14) + (k << 8) + hh * 64;
        const float* av = ((j < 4) ? al : ar) + (l << 8) + hh * 64;
        float s = 0.f;
        #pragma unroll 8
        for (int f = 0; f < 64; ++f) s = fmaf(wrow[f], av[f], s);
        WAB[i] = s;
    }
    int i2 = i - 4 * 64 * 8;
    if (i2 >= 0 && i2 < 4 * 64) {
        int l = i2 >> 6, f = i2 & 63;
        float s = 0.f;
        #pragma unroll
        for (int h = 0; h < 4; ++h) s += bias[(l << 8) + h * 64 + f];
        bsum[i2] = s;
    }
}

// ================= per-layer kernels =================

// ft = h @ W. Block = 256 thr = 4 waves, 32-row chunk. No W staging:
// W rows from global (L1-hot, wave-uniform row per k-step). hT[k][row]
// stride 36 (conflict-free). Wave w: rows w*8..w*8+7, lane: cols lane*4..+3.
// el/er fused via precomputed WAB. launch_bounds(256,4): VGPR cap 128, no spill.
__global__ __launch_bounds__(256, 4) void k_gemm(
        const float* __restrict__ h, const float* __restrict__ Wt,
        const float* __restrict__ WAB,
        __half* __restrict__ ft, float* __restrict__ el, float* __restrict__ er,
        int n) {
    __shared__ float hT[64 * 36];     // 9.2KB, [k][row], row in 0..31
    __shared__ float wab[512];        // 2KB
    int t = threadIdx.x, w = t >> 6, lane = t & 63;
    int r0 = blockIdx.x * 32;

    if (t < 128) ((float4*)wab)[t] = ((const float4*)WAB)[t];

    // stage hT: thread -> row r=t&31, k-range kq*8..+7.
    // banks (4k+r)%32: per store instr, lanes cover all 32 banks twice -> free.
    {
        int r = t & 31, kq = t >> 5;
        int gr = r0 + r;
        float4 a = make_float4(0.f, 0.f, 0.f, 0.f);
        float4 b = make_float4(0.f, 0.f, 0.f, 0.f);
        if (gr < n) {
            const float4* hp = (const float4*)(h + (size_t)gr * 64 + kq * 8);
            a = hp[0]; b = hp[1];
        }
        int k0 = kq * 8;
        hT[(k0 + 0) * 36 + r] = a.x; hT[(k0 + 1) * 36 + r] = a.y;
        hT[(k0 + 2) * 36 + r] = a.z; hT[(k0 + 3) * 36 + r] = a.w;
        hT[(k0 + 4) * 36 + r] = b.x; hT[(k0 + 5) * 36 + r] = b.y;
        hT[(k0 + 6) * 36 + r] = b.z; hT[(k0 + 7) * 36 + r] = b.w;
    }
    __syncthreads();

    float4 acc[8];
    #pragma unroll
    for (int j = 0; j < 8; ++j) acc[j] = make_float4(0.f, 0.f, 0.f, 0.f);
    int c0 = lane << 2;
    int hbase = w * 8;
    const float* Wp = Wt + c0;

    #pragma unroll 8
    for (int k = 0; k < 64; ++k) {
        float4 w4 = *(const float4*)(Wp + (k << 8));            // global, L1-hot
        float4 ha = *(const float4*)&hT[k * 36 + hbase];        // uniform b128
        float4 hb = *(const float4*)&hT[k * 36 + hbase + 4];
        #define FMA4(A, s) { A.x = fmaf(s, w4.x, A.x); A.y = fmaf(s, w4.y, A.y); \
                             A.z = fmaf(s, w4.z, A.z); A.w = fmaf(s, w4.w, A.w); }
        FMA4(acc[0], ha.x) FMA4(acc[1], ha.y) FMA4(acc[2], ha.z) FMA4(acc[3], ha.w)
        FMA4(acc[4], hb.x) FMA4(acc[5], hb.y) FMA4(acc[6], hb.z) FMA4(acc[7], hb.w)
        #undef FMA4
    }

    // store ft as fp16 (contiguous 512B per wave per j)
    #pragma unroll
    for (int j = 0; j < 8; ++j) {
        int gr = r0 + hbase + j;
        if (gr < n) {
            __half2 lo = __floats2half2_rn(acc[j].x, acc[j].y);
            __half2 hi = __floats2half2_rn(acc[j].z, acc[j].w);
            uint2 v = make_uint2(*(unsigned*)&lo, *(unsigned*)&hi);
            *(uint2*)(ft + (size_t)gr * 256 + c0) = v;
        }
    }

    // el/er: thread -> (row r2 = t&31, j = t>>5); conflict-free hT reads
    int r2 = t & 31, j = t >> 5;
    float s = 0.f;
    #pragma unroll 8
    for (int k = 0; k < 64; ++k) s = fmaf(hT[k * 36 + r2], wab[(k << 3) + j], s);
    int gr2 = r0 + r2;
    if (gr2 < n) {
        float* dstp = (j < 4) ? el : er;
        dstp[(size_t)gr2 * 4 + (j & 3)] = s;
    }
}

// Fused edge-softmax + aggregation + bias. One wave per dst node.
// Chunk 0 (deg<=16, ~97% of nodes): src idx + e-values in registers,
// gather loop fully unrolled (fixed 16 iters, uniform-branch skip) for MLP.
__global__ __launch_bounds__(256) void k_agg(
        const int* __restrict__ rowptr, const int* __restrict__ csr_src,
        const float* __restrict__ el, const float* __restrict__ er,
        const __half* __restrict__ ft, const float* __restrict__ bsum,
        float* __restrict__ out, int n) {
    __shared__ float lds_ee[4][64];
    __shared__ int   lds_s[4][16];
    int wid  = (int)((blockIdx.x * blockDim.x + threadIdx.x) >> 6);
    int w    = (threadIdx.x >> 6) & 3;
    int lane = threadIdx.x & 63;
    if (wid >= n) return;
    int d = wid;
    int rbeg = rowptr[d], rend = rowptr[d + 1];
    float bs = bsum[lane];
    if (rend == rbeg) { out[(size_t)d * 64 + lane] = bs; return; }

    int ei = lane >> 2, hh = lane & 3;
    float erh = er[(size_t)d * 4 + hh];

    // ---- chunk 0 in registers ----
    int sfb = csr_src[rbeg];               // fallback src (valid, cached)
    int idx0 = rbeg + ei;
    bool v0 = idx0 < rend;
    int s0 = v0 ? csr_src[idx0] : sfb;
    float x0 = el[(size_t)s0 * 4 + hh] + erh;
    x0 = x0 > 0.f ? x0 : NEG_SLOPE * x0;

    // pass 1: per-head max
    float m = v0 ? x0 : -FINF;
    for (int base = rbeg + 16; base < rend; base += 16) {
        int idx = base + ei;
        if (idx < rend) {
            int s = csr_src[idx];
            float x = el[(size_t)s * 4 + hh] + erh;
            x = x > 0.f ? x : NEG_SLOPE * x;
            m = fmaxf(m, x);
        }
    }
    #pragma unroll
    for (int msk = 4; msk < 64; msk <<= 1) m = fmaxf(m, __shfl_xor(m, msk));

    // pass 2: chunk 0 unrolled (srcs via shuffle, ee via LDS), tail dynamic
    float ee0 = v0 ? __expf(x0 - m) : 0.f;
    float dsum = ee0;
    lds_ee[w][lane] = ee0;
    float4 acc = make_float4(0.f, 0.f, 0.f, 0.f);
    int csz = min(16, rend - rbeg);        // wave-uniform
    #pragma unroll
    for (int i = 0; i < 16; ++i) {
        if (i < csz) {
            int s = __shfl(s0, i << 2);
            float4 ee4 = *(float4*)&lds_ee[w][i * 4];
            uint2 u = *(const uint2*)(ft + (size_t)s * 256 + (lane << 2));
            float2 fa = __half22float2(*(__half2*)&u.x);
            float2 fb = __half22float2(*(__half2*)&u.y);
            acc.x += ee4.x * fa.x; acc.y += ee4.y * fa.y;
            acc.z += ee4.z * fb.x; acc.w += ee4.w * fb.y;
        }
    }
    for (int base = rbeg + 16; base < rend; base += 16) {
        int idx = base + ei;
        int e16 = min(16, rend - base);
        float ee = 0.f;
        if (idx < rend) {
            int s = csr_src[idx];
            float x = el[(size_t)s * 4 + hh] + erh;
            x = x > 0.f ? x : NEG_SLOPE * x;
            ee = __expf(x - m);
            if (hh == 0) lds_s[w][ei] = s;
        }
        dsum += ee;
        lds_ee[w][lane] = ee;
        for (int i = 0; i < e16; ++i) {
            float4 ee4 = *(float4*)&lds_ee[w][i * 4];
            int s = lds_s[w][i];
            uint2 u = *(const uint2*)(ft + (size_t)s * 256 + (lane << 2));
            float2 fa = __half22float2(*(__half2*)&u.x);
            float2 fb = __half22float2(*(__half2*)&u.y);
            acc.x += ee4.x * fa.x; acc.y += ee4.y * fa.y;
            acc.z += ee4.z * fb.x; acc.w += ee4.w * fb.y;
        }
    }
    #pragma unroll
    for (int msk = 4; msk < 64; msk <<= 1) dsum += __shfl_xor(dsum, msk);
    float d0 = __shfl(dsum, 0), d1 = __shfl(dsum, 1);
    float d2 = __shfl(dsum, 2), d3 = __shfl(dsum, 3);
    out[(size_t)d * 64 + lane] = acc.x / d0 + acc.y / d1 + acc.z / d2 + acc.w / d3 + bs;
}

// ================= launcher =================

extern "C" void kernel_launch(void* const* d_in, const int* in_sizes, int n_in,
                              void* d_out, int out_size, void* d_ws, size_t ws_size,
                              hipStream_t stream) {
    const float* feat = (const float*)d_in[0];
    const float* W    = (const float*)d_in[1];
    const float* al   = (const float*)d_in[2];
    const float* ar   = (const float*)d_in[3];
    const float* bias = (const float*)d_in[4];
    const int*   src  = (const int*)d_in[5];
    const int*   dst  = (const int*)d_in[6];
    float* out = (float*)d_out;

    const int N = in_sizes[0] / 64;   // 50000
    const int E = in_sizes[5];        // 500000
    const int L = 4;

    // workspace carve
    float* ws = (float*)d_ws;
    __half* ft = (__half*)ws;                          // N*256 halves = N*128 floats
    float* hA   = ws + (size_t)N * 128;                // N*64
    float* hB   = hA + (size_t)N * 64;                 // N*64
    float* el   = hB + (size_t)N * 64;                 // N*4
    float* er   = el + (size_t)N * 4;                  // N*4
    float* Wt   = er + (size_t)N * 4;                  // 4*16384
    float* WAB  = Wt + 4 * 16384;                      // 4*512
    float* bsum = WAB + 4 * 512;                       // 4*64
    int* rowptr  = (int*)(bsum + 4 * 64);              // N+1
    int* cursor  = rowptr + (N + 1);                   // N
    int* deg     = cursor + N;                         // N
    int* csr_src = deg + N;                            // E

    // ---- prologue: CSR build + weight prep (once per call) ----
    hipMemsetAsync(deg, 0, (size_t)N * sizeof(int), stream);
    k_deg<<<(E + 255) / 256, 256, 0, stream>>>(dst, deg, E);
    k_scan<<<1, 1024, 0, stream>>>(deg, rowptr, cursor, N);
    k_scatter<<<(E + 255) / 256, 256, 0, stream>>>(src, dst, cursor, csr_src, E);
    k_transW<<<(4 * 64 * 256 + 255) / 256, 256, 0, stream>>>(W, Wt);
    k_prep<<<(4 * 64 * 8 + 4 * 64 + 255) / 256, 256, 0, stream>>>(
        W, al, ar, bias, WAB, bsum);

    // ---- layers ----
    const float* hin = feat;
    for (int l = 0; l < L; ++l) {
        float* hout = (l == L - 1) ? out : ((l & 1) ? hB : hA);
        k_gemm<<<(N + 31) / 32, 256, 0, stream>>>(
            hin, Wt + (size_t)l * 16384, WAB + (size_t)l * 512,
            ft, el, er, N);
        k_agg<<<((size_t)N * 64 + 255) / 256, 256, 0, stream>>>(
            rowptr, csr_src, el, er, ft, bsum + (size_t)l * 64, hout, N);
        hin = hout;
    }
}

// Round 7
// 414.041 us; speedup vs baseline: 1.0948x; 1.0948x over previous
//
#include <hip/hip_runtime.h>
#include <hip/hip_fp16.h>

#define NEG_SLOPE 0.2f
#define FINF __builtin_inff()

// ================= prologue kernels (once per call) =================

__global__ __launch_bounds__(256) void k_deg(const int* __restrict__ dst,
                                             int* __restrict__ deg, int ne) {
    int e = blockIdx.x * blockDim.x + threadIdx.x;
    if (e < ne) atomicAdd(&deg[dst[e]], 1);
}

__global__ __launch_bounds__(1024) void k_scan(const int* __restrict__ deg,
                                               int* __restrict__ rowptr,
                                               int* __restrict__ cursor, int n) {
    __shared__ int wsum[16];
    __shared__ int carry_s;
    int t = threadIdx.x, lane = t & 63, w = t >> 6;
    if (t == 0) carry_s = 0;
    __syncthreads();
    for (int base = 0; base < n; base += 4096) {
        int i0 = base + t * 4;
        int4 v;
        v.x = (i0 + 0 < n) ? deg[i0 + 0] : 0;
        v.y = (i0 + 1 < n) ? deg[i0 + 1] : 0;
        v.z = (i0 + 2 < n) ? deg[i0 + 2] : 0;
        v.w = (i0 + 3 < n) ? deg[i0 + 3] : 0;
        int tsum = v.x + v.y + v.z + v.w;
        int s = tsum;
        #pragma unroll
        for (int off = 1; off < 64; off <<= 1) {
            int y = __shfl_up(s, off);
            if (lane >= off) s += y;
        }
        if (lane == 63) wsum[w] = s;
        __syncthreads();
        if (w == 0 && lane < 16) {
            int ws = wsum[lane];
            #pragma unroll
            for (int off = 1; off < 16; off <<= 1) {
                int y = __shfl_up(ws, off);
                if (lane >= off) ws += y;
            }
            wsum[lane] = ws;
        }
        __syncthreads();
        int carry = carry_s;
        int wexcl = (w > 0) ? wsum[w - 1] : 0;
        int excl = carry + wexcl + (s - tsum);
        int e0 = excl;
        int e1 = e0 + v.x;
        int e2 = e1 + v.y;
        int e3 = e2 + v.z;
        if (i0 + 0 < n) { rowptr[i0 + 0] = e0; cursor[i0 + 0] = e0; }
        if (i0 + 1 < n) { rowptr[i0 + 1] = e1; cursor[i0 + 1] = e1; }
        if (i0 + 2 < n) { rowptr[i0 + 2] = e2; cursor[i0 + 2] = e2; }
        if (i0 + 3 < n) { rowptr[i0 + 3] = e3; cursor[i0 + 3] = e3; }
        __syncthreads();
        if (t == 0) carry_s = carry + wsum[15];
        __syncthreads();
    }
    if (t == 0) rowptr[n] = carry_s;
}

__global__ __launch_bounds__(256) void k_scatter(const int* __restrict__ src,
                                                 const int* __restrict__ dst,
                                                 int* __restrict__ cursor,
                                                 int* __restrict__ csr_src, int ne) {
    int e = blockIdx.x * blockDim.x + threadIdx.x;
    if (e >= ne) return;
    int pos = atomicAdd(&cursor[dst[e]], 1);
    csr_src[pos] = src[e];
}

// W[l][k][h*64+f] -> Wt[l][k][f*4+h]   (all 4 layers)
__global__ __launch_bounds__(256) void k_transW(const float* __restrict__ W,
                                                float* __restrict__ Wt) {
    int i = blockIdx.x * blockDim.x + threadIdx.x;
    if (i >= 4 * 64 * 256) return;
    int l = i >> 14, r = i & 16383;
    int k = r >> 8, c = r & 255;
    int f = c >> 2, h = c & 3;
    Wt[i] = W[(l << 14) + (k << 8) + h * 64 + f];
}

// WAB[l][k][j]: j<4 -> sum_f W[l][k][j*64+f]*al[l][j][f]; j>=4 -> ar (head j-4)
// bsum[l][f] = sum_h bias[l][h][f]
__global__ __launch_bounds__(256) void k_prep(const float* __restrict__ W,
                                              const float* __restrict__ al,
                                              const float* __restrict__ ar,
                                              const float* __restrict__ bias,
                                              float* __restrict__ WAB,
                                              float* __restrict__ bsum) {
    int i = blockIdx.x * blockDim.x + threadIdx.x;
    if (i < 4 * 64 * 8) {
        int l = i >> 9, r = i & 511;
        int k = r >> 3, j = r & 7;
        int hh = j & 3;
        const float* wrow = W + (l << 14) + (k << 8) + hh * 64;
        const float* av = ((j < 4) ? al : ar) + (l << 8) + hh * 64;
        float s = 0.f;
        #pragma unroll 8
        for (int f = 0; f < 64; ++f) s = fmaf(wrow[f], av[f], s);
        WAB[i] = s;
    }
    int i2 = i - 4 * 64 * 8;
    if (i2 >= 0 && i2 < 4 * 64) {
        int l = i2 >> 6, f = i2 & 63;
        float s = 0.f;
        #pragma unroll
        for (int h = 0; h < 4; ++h) s += bias[(l << 8) + h * 64 + f];
        bsum[i2] = s;
    }
}

// ================= per-layer kernels =================

// ft = h @ W. Block = 256 thr = 4 waves, 64-row chunk, 16 rows per wave.
// W rows from global (L1/L2-hot, one float4 per lane per k; row shared by
// 4 waves x 16 rows). hT[k][row] stride 68 (conflict-free staging + broadcast
// reads). acc[16] = 64 VGPRs; launch_bounds(256,4) caps at 128 -> no spill.
__global__ __launch_bounds__(256, 4) void k_gemm(
        const float* __restrict__ h, const float* __restrict__ Wt,
        const float* __restrict__ WAB,
        __half* __restrict__ ft, float* __restrict__ el, float* __restrict__ er,
        int n) {
    __shared__ float hT[64 * 68];     // 17.4KB, [k][row], row 0..63
    __shared__ float wab[512];        // 2KB
    int t = threadIdx.x, w = t >> 6, lane = t & 63;
    int r0 = blockIdx.x * 64;

    if (t < 128) ((float4*)wab)[t] = ((const float4*)WAB)[t];

    // stage hT: thread -> row r=t&63, k-range kq*16..+15.
    // store banks (4k+r)%32: lanes vary r -> 2 lanes/bank (free).
    {
        int r = t & 63, kq = t >> 6;
        int gr = r0 + r;
        float4 a = make_float4(0.f, 0.f, 0.f, 0.f), b = a, c = a, d = a;
        if (gr < n) {
            const float4* hp = (const float4*)(h + (size_t)gr * 64 + kq * 16);
            a = hp[0]; b = hp[1]; c = hp[2]; d = hp[3];
        }
        int k0 = kq * 16;
        hT[(k0 +  0) * 68 + r] = a.x; hT[(k0 +  1) * 68 + r] = a.y;
        hT[(k0 +  2) * 68 + r] = a.z; hT[(k0 +  3) * 68 + r] = a.w;
        hT[(k0 +  4) * 68 + r] = b.x; hT[(k0 +  5) * 68 + r] = b.y;
        hT[(k0 +  6) * 68 + r] = b.z; hT[(k0 +  7) * 68 + r] = b.w;
        hT[(k0 +  8) * 68 + r] = c.x; hT[(k0 +  9) * 68 + r] = c.y;
        hT[(k0 + 10) * 68 + r] = c.z; hT[(k0 + 11) * 68 + r] = c.w;
        hT[(k0 + 12) * 68 + r] = d.x; hT[(k0 + 13) * 68 + r] = d.y;
        hT[(k0 + 14) * 68 + r] = d.z; hT[(k0 + 15) * 68 + r] = d.w;
    }
    __syncthreads();

    float4 acc[16];
    #pragma unroll
    for (int j = 0; j < 16; ++j) acc[j] = make_float4(0.f, 0.f, 0.f, 0.f);
    int c0 = lane << 2;
    int hbase = w * 16;
    const float* Wp = Wt + c0;

    #pragma unroll 4
    for (int k = 0; k < 64; ++k) {
        float4 w4 = *(const float4*)(Wp + (k << 8));          // global, L1-hot
        float4 h0 = *(const float4*)&hT[k * 68 + hbase];      // broadcast b128
        float4 h1 = *(const float4*)&hT[k * 68 + hbase + 4];
        float4 h2 = *(const float4*)&hT[k * 68 + hbase + 8];
        float4 h3 = *(const float4*)&hT[k * 68 + hbase + 12];
        #define FMA4(A, s) { A.x = fmaf(s, w4.x, A.x); A.y = fmaf(s, w4.y, A.y); \
                             A.z = fmaf(s, w4.z, A.z); A.w = fmaf(s, w4.w, A.w); }
        FMA4(acc[ 0], h0.x) FMA4(acc[ 1], h0.y) FMA4(acc[ 2], h0.z) FMA4(acc[ 3], h0.w)
        FMA4(acc[ 4], h1.x) FMA4(acc[ 5], h1.y) FMA4(acc[ 6], h1.z) FMA4(acc[ 7], h1.w)
        FMA4(acc[ 8], h2.x) FMA4(acc[ 9], h2.y) FMA4(acc[10], h2.z) FMA4(acc[11], h2.w)
        FMA4(acc[12], h3.x) FMA4(acc[13], h3.y) FMA4(acc[14], h3.z) FMA4(acc[15], h3.w)
        #undef FMA4
    }

    // store ft as fp16
    #pragma unroll
    for (int j = 0; j < 16; ++j) {
        int gr = r0 + hbase + j;
        if (gr < n) {
            __half2 lo = __floats2half2_rn(acc[j].x, acc[j].y);
            __half2 hi = __floats2half2_rn(acc[j].z, acc[j].w);
            uint2 v = make_uint2(*(unsigned*)&lo, *(unsigned*)&hi);
            *(uint2*)(ft + (size_t)gr * 256 + c0) = v;
        }
    }

    // el/er: thread -> row r2=t&63, j in {t>>6, t>>6+4}; conflict-free reads
    int r2 = t & 63;
    #pragma unroll
    for (int jj = 0; jj < 2; ++jj) {
        int j = (t >> 6) + jj * 4;
        float s = 0.f;
        #pragma unroll 8
        for (int k = 0; k < 64; ++k) s = fmaf(hT[k * 68 + r2], wab[(k << 3) + j], s);
        int gr2 = r0 + r2;
        if (gr2 < n) {
            float* dstp = (jj == 0) ? el : er;
            dstp[(size_t)gr2 * 4 + (j & 3)] = s;
        }
    }
}

// Fused edge-softmax + aggregation + bias. One wave per dst node.
// First 16-edge chunk kept in registers across both passes (deg<=16 is ~97%).
__global__ __launch_bounds__(256) void k_agg(
        const int* __restrict__ rowptr, const int* __restrict__ csr_src,
        const float* __restrict__ el, const float* __restrict__ er,
        const __half* __restrict__ ft, const float* __restrict__ bsum,
        float* __restrict__ out, int n) {
    __shared__ float lds_ee[4][64];
    __shared__ int   lds_s[4][16];
    int wid  = (int)((blockIdx.x * blockDim.x + threadIdx.x) >> 6);
    int w    = (threadIdx.x >> 6) & 3;
    int lane = threadIdx.x & 63;
    if (wid >= n) return;
    int d = wid;
    int rbeg = rowptr[d], rend = rowptr[d + 1];
    float bs = bsum[lane];
    if (rend == rbeg) { out[(size_t)d * 64 + lane] = bs; return; }

    int ei = lane >> 2, hh = lane & 3;
    float erh = er[(size_t)d * 4 + hh];

    // pass 1: per-head max; chunk 0 cached in registers
    int s0 = -1; float x0 = 0.f;
    float m = -FINF;
    {
        int idx = rbeg + ei;
        if (idx < rend) {
            s0 = csr_src[idx];
            float x = el[(size_t)s0 * 4 + hh] + erh;
            x0 = x > 0.f ? x : NEG_SLOPE * x;
            m = x0;
        }
    }
    for (int base = rbeg + 16; base < rend; base += 16) {
        int idx = base + ei;
        if (idx < rend) {
            int s = csr_src[idx];
            float x = el[(size_t)s * 4 + hh] + erh;
            x = x > 0.f ? x : NEG_SLOPE * x;
            m = fmaxf(m, x);
        }
    }
    #pragma unroll
    for (int msk = 4; msk < 64; msk <<= 1) m = fmaxf(m, __shfl_xor(m, msk));

    // pass 2: chunk 0 from registers, rest re-gathered
    float dsum = 0.f;
    float4 acc = make_float4(0.f, 0.f, 0.f, 0.f);
    {
        float ee = 0.f;
        if (s0 >= 0) {
            ee = __expf(x0 - m);
            dsum += ee;
            if (hh == 0) lds_s[w][ei] = s0;
        }
        lds_ee[w][lane] = ee;
        int e16 = min(16, rend - rbeg);
        for (int i = 0; i < e16; ++i) {
            float4 ee4 = *(float4*)&lds_ee[w][i * 4];
            int s = lds_s[w][i];
            uint2 u = *(const uint2*)(ft + (size_t)s * 256 + (lane << 2));
            float2 fa = __half22float2(*(__half2*)&u.x);
            float2 fb = __half22float2(*(__half2*)&u.y);
            acc.x += ee4.x * fa.x; acc.y += ee4.y * fa.y;
            acc.z += ee4.z * fb.x; acc.w += ee4.w * fb.y;
        }
    }
    for (int base = rbeg + 16; base < rend; base += 16) {
        int idx = base + ei;
        int e16 = min(16, rend - base);
        float ee = 0.f;
        if (idx < rend) {
            int s = csr_src[idx];
            float x = el[(size_t)s * 4 + hh] + erh;
            x = x > 0.f ? x : NEG_SLOPE * x;
            ee = __expf(x - m);
            dsum += ee;
            if (hh == 0) lds_s[w][ei] = s;
        }
        lds_ee[w][lane] = ee;
        for (int i = 0; i < e16; ++i) {
            float4 ee4 = *(float4*)&lds_ee[w][i * 4];
            int s = lds_s[w][i];
            uint2 u = *(const uint2*)(ft + (size_t)s * 256 + (lane << 2));
            float2 fa = __half22float2(*(__half2*)&u.x);
            float2 fb = __half22float2(*(__half2*)&u.y);
            acc.x += ee4.x * fa.x; acc.y += ee4.y * fa.y;
            acc.z += ee4.z * fb.x; acc.w += ee4.w * fb.y;
        }
    }
    #pragma unroll
    for (int msk = 4; msk < 64; msk <<= 1) dsum += __shfl_xor(dsum, msk);
    float d0 = __shfl(dsum, 0), d1 = __shfl(dsum, 1);
    float d2 = __shfl(dsum, 2), d3 = __shfl(dsum, 3);
    out[(size_t)d * 64 + lane] = acc.x / d0 + acc.y / d1 + acc.z / d2 + acc.w / d3 + bs;
}

// ================= launcher =================

extern "C" void kernel_launch(void* const* d_in, const int* in_sizes, int n_in,
                              void* d_out, int out_size, void* d_ws, size_t ws_size,
                              hipStream_t stream) {
    const float* feat = (const float*)d_in[0];
    const float* W    = (const float*)d_in[1];
    const float* al   = (const float*)d_in[2];
    const float* ar   = (const float*)d_in[3];
    const float* bias = (const float*)d_in[4];
    const int*   src  = (const int*)d_in[5];
    const int*   dst  = (const int*)d_in[6];
    float* out = (float*)d_out;

    const int N = in_sizes[0] / 64;   // 50000
    const int E = in_sizes[5];        // 500000
    const int L = 4;

    // workspace carve
    float* ws = (float*)d_ws;
    __half* ft = (__half*)ws;                          // N*256 halves = N*128 floats
    float* hA   = ws + (size_t)N * 128;                // N*64
    float* hB   = hA + (size_t)N * 64;                 // N*64
    float* el   = hB + (size_t)N * 64;                 // N*4
    float* er   = el + (size_t)N * 4;                  // N*4
    float* Wt   = er + (size_t)N * 4;                  // 4*16384
    float* WAB  = Wt + 4 * 16384;                      // 4*512
    float* bsum = WAB + 4 * 512;                       // 4*64
    int* rowptr  = (int*)(bsum + 4 * 64);              // N+1
    int* cursor  = rowptr + (N + 1);                   // N
    int* deg     = cursor + N;                         // N
    int* csr_src = deg + N;                            // E

    // ---- prologue: CSR build + weight prep (once per call) ----
    hipMemsetAsync(deg, 0, (size_t)N * sizeof(int), stream);
    k_deg<<<(E + 255) / 256, 256, 0, stream>>>(dst, deg, E);
    k_scan<<<1, 1024, 0, stream>>>(deg, rowptr, cursor, N);
    k_scatter<<<(E + 255) / 256, 256, 0, stream>>>(src, dst, cursor, csr_src, E);
    k_transW<<<(4 * 64 * 256 + 255) / 256, 256, 0, stream>>>(W, Wt);
    k_prep<<<(4 * 64 * 8 + 4 * 64 + 255) / 256, 256, 0, stream>>>(
        W, al, ar, bias, WAB, bsum);

    // ---- layers ----
    const float* hin = feat;
    for (int l = 0; l < L; ++l) {
        float* hout = (l == L - 1) ? out : ((l & 1) ? hB : hA);
        k_gemm<<<(N + 63) / 64, 256, 0, stream>>>(
            hin, Wt + (size_t)l * 16384, WAB + (size_t)l * 512,
            ft, el, er, N);
        k_agg<<<((size_t)N * 64 + 255) / 256, 256, 0, stream>>>(
            rowptr, csr_src, el, er, ft, bsum + (size_t)l * 64, hout, N);
        hin = hout;
    }
}

// Round 8
// 307.985 us; speedup vs baseline: 1.4718x; 1.3444x over previous
//
#include <hip/hip_runtime.h>
#include <hip/hip_fp16.h>

#define NEG_SLOPE 0.2f
#define FINF __builtin_inff()

typedef _Float16 f16x8 __attribute__((ext_vector_type(8)));
typedef float f32x4 __attribute__((ext_vector_type(4)));

// ================= prologue kernels (once per call) =================

__global__ __launch_bounds__(256) void k_deg(const int* __restrict__ dst,
                                             int* __restrict__ deg, int ne) {
    int e = blockIdx.x * blockDim.x + threadIdx.x;
    if (e < ne) atomicAdd(&deg[dst[e]], 1);
}

// hierarchical scan: 2048 elems/block
#define SCB 2048
__global__ __launch_bounds__(256) void k_scan1(const int* __restrict__ deg,
                                               int* __restrict__ bsums, int n) {
    __shared__ int wsum[4];
    int b = blockIdx.x, t = threadIdx.x;
    int i0 = b * SCB + t * 8;
    int s = 0;
    #pragma unroll
    for (int j = 0; j < 8; ++j) { int i = i0 + j; if (i < n) s += deg[i]; }
    #pragma unroll
    for (int m = 1; m < 64; m <<= 1) s += __shfl_xor(s, m);
    if ((t & 63) == 0) wsum[t >> 6] = s;
    __syncthreads();
    if (t == 0) bsums[b] = wsum[0] + wsum[1] + wsum[2] + wsum[3];
}

__global__ __launch_bounds__(64) void k_scan2(const int* __restrict__ bsums,
                                              int* __restrict__ boff,
                                              int* __restrict__ rowptr,
                                              int nb, int n) {
    int t = threadIdx.x;
    int v = (t < nb) ? bsums[t] : 0;
    int s = v;
    #pragma unroll
    for (int m = 1; m < 64; m <<= 1) { int y = __shfl_up(s, m); if (t >= m) s += y; }
    if (t < nb) boff[t] = s - v;
    if (t == 63) rowptr[n] = s;   // grand total
}

__global__ __launch_bounds__(256) void k_scan3(const int* __restrict__ deg,
                                               const int* __restrict__ boff,
                                               int* __restrict__ rowptr,
                                               int* __restrict__ cursor, int n) {
    __shared__ int woff[4];
    int b = blockIdx.x, t = threadIdx.x, lane = t & 63, w = t >> 6;
    int i0 = b * SCB + t * 8;
    int v[8]; int s8 = 0;
    #pragma unroll
    for (int j = 0; j < 8; ++j) { int i = i0 + j; v[j] = (i < n) ? deg[i] : 0; s8 += v[j]; }
    int s = s8;
    #pragma unroll
    for (int m = 1; m < 64; m <<= 1) { int y = __shfl_up(s, m); if (lane >= m) s += y; }
    if (lane == 63) woff[w] = s;
    __syncthreads();
    int wo = 0;
    #pragma unroll
    for (int k = 0; k < 4; ++k) if (k < w) wo += woff[k];
    int excl = boff[b] + wo + s - s8;
    #pragma unroll
    for (int j = 0; j < 8; ++j) {
        int i = i0 + j;
        if (i < n) { rowptr[i] = excl; cursor[i] = excl; }
        excl += v[j];
    }
}

__global__ __launch_bounds__(256) void k_scatter(const int* __restrict__ src,
                                                 const int* __restrict__ dst,
                                                 int* __restrict__ cursor,
                                                 int* __restrict__ csr_src, int ne) {
    int e = blockIdx.x * blockDim.x + threadIdx.x;
    if (e >= ne) return;
    int pos = atomicAdd(&cursor[dst[e]], 1);
    csr_src[pos] = src[e];
}

// WAB[l][k][j]: j<4 -> sum_f W[l][k][j*64+f]*al[l][j][f]; j>=4 -> ar (head j-4)
// bsum[l][f] = sum_h bias[l][h][f]
__global__ __launch_bounds__(256) void k_prep(const float* __restrict__ W,
                                              const float* __restrict__ al,
                                              const float* __restrict__ ar,
                                              const float* __restrict__ bias,
                                              float* __restrict__ WAB,
                                              float* __restrict__ bsum) {
    int i = blockIdx.x * blockDim.x + threadIdx.x;
    if (i < 4 * 64 * 8) {
        int l = i >> 9, r = i & 511;
        int k = r >> 3, j = r & 7;
        int hh = j & 3;
        const float* wrow = W + (l << 14) + (k << 8) + hh * 64;
        const float* av = ((j < 4) ? al : ar) + (l << 8) + hh * 64;
        float s = 0.f;
        #pragma unroll 8
        for (int f = 0; f < 64; ++f) s = fmaf(wrow[f], av[f], s);
        WAB[i] = s;
    }
    int i2 = i - 4 * 64 * 8;
    if (i2 >= 0 && i2 < 4 * 64) {
        int l = i2 >> 6, f = i2 & 63;
        float s = 0.f;
        #pragma unroll
        for (int h = 0; h < 4; ++h) s += bias[(l << 8) + h * 64 + f];
        bsum[i2] = s;
    }
}

// Pack W into fp16 MFMA B-fragment order.
// Wf idx = (l*4096... per layer 16384): ((kc*16+ct)*64 + lane)*8 + j
// value = W_perm[k = kc*32 + (lane>>4)*8 + j][c = ct*16 + (lane&15)],
// where output col c = f*4+h  <->  original col h*64+f.
__global__ __launch_bounds__(256) void k_packW(const float* __restrict__ W,
                                               _Float16* __restrict__ Wf) {
    int i = blockIdx.x * blockDim.x + threadIdx.x;
    if (i >= 4 * 16384) return;
    int l = i >> 14, r = i & 16383;
    int j = r & 7, lane = (r >> 3) & 63, ct = (r >> 9) & 15, kc = r >> 13;
    int k = kc * 32 + (lane >> 4) * 8 + j;
    int c = ct * 16 + (lane & 15);
    int f = c >> 2, hh = c & 3;
    Wf[i] = (_Float16)W[(l << 14) + (k << 8) + hh * 64 + f];
}

// Pack WAB into fp16 B-fragment (cols 0..7 = WAB, cols 8..15 = 0).
// WABf idx per layer 1024: ((kc)*64 + lane)*8 + j
__global__ __launch_bounds__(256) void k_packAB(const float* __restrict__ WAB,
                                                _Float16* __restrict__ WABf) {
    int i = blockIdx.x * blockDim.x + threadIdx.x;
    if (i >= 4 * 1024) return;
    int l = i >> 10, r = i & 1023;
    int j = r & 7, lane = (r >> 3) & 63, kc = r >> 9;
    int k = kc * 32 + (lane >> 4) * 8 + j;
    int col = lane & 15;
    float v = (col < 8) ? WAB[(l << 9) + (k << 3) + col] : 0.f;
    WABf[i] = (_Float16)v;
}

// ================= per-layer kernels =================

// ft = h @ W via MFMA f16. Block 256 = 4 waves; wave -> 16 rows.
// A (h rows, f32->f16) loaded per-lane from global; B from pre-packed Wf.
// el/er via 2 extra MFMAs against zero-padded WABf. No LDS, no shuffles.
// A/B share the same assumed k-mapping so any k-permutation cancels.
__global__ __launch_bounds__(256) void k_gemm(
        const float* __restrict__ h, const _Float16* __restrict__ Wf,
        const _Float16* __restrict__ WABf,
        _Float16* __restrict__ ft, float* __restrict__ el, float* __restrict__ er,
        int n) {
    int t = threadIdx.x, w = t >> 6, lane = t & 63;
    int r0 = blockIdx.x * 64 + w * 16;
    if (r0 >= n) return;
    int m = lane & 15, kb = lane >> 4;
    int gr = r0 + m;

    f16x8 A0, A1;
    if (gr < n) {
        const float* hp = h + (size_t)gr * 64 + kb * 8;
        float4 p0 = *(const float4*)(hp);
        float4 p1 = *(const float4*)(hp + 4);
        float4 q0 = *(const float4*)(hp + 32);
        float4 q1 = *(const float4*)(hp + 36);
        A0[0] = (_Float16)p0.x; A0[1] = (_Float16)p0.y;
        A0[2] = (_Float16)p0.z; A0[3] = (_Float16)p0.w;
        A0[4] = (_Float16)p1.x; A0[5] = (_Float16)p1.y;
        A0[6] = (_Float16)p1.z; A0[7] = (_Float16)p1.w;
        A1[0] = (_Float16)q0.x; A1[1] = (_Float16)q0.y;
        A1[2] = (_Float16)q0.z; A1[3] = (_Float16)q0.w;
        A1[4] = (_Float16)q1.x; A1[5] = (_Float16)q1.y;
        A1[6] = (_Float16)q1.z; A1[7] = (_Float16)q1.w;
    } else {
        #pragma unroll
        for (int j = 0; j < 8; ++j) { A0[j] = (_Float16)0.f; A1[j] = (_Float16)0.f; }
    }

    // el/er (2 MFMA)
    {
        f16x8 wb0 = *(const f16x8*)(WABf + lane * 8);
        f16x8 wb1 = *(const f16x8*)(WABf + 512 + lane * 8);
        f32x4 e; e[0] = 0.f; e[1] = 0.f; e[2] = 0.f; e[3] = 0.f;
        e = __builtin_amdgcn_mfma_f32_16x16x32_f16(A0, wb0, e, 0, 0, 0);
        e = __builtin_amdgcn_mfma_f32_16x16x32_f16(A1, wb1, e, 0, 0, 0);
        if (m < 8) {
            float* dp = (m < 4) ? el : er;
            #pragma unroll
            for (int r = 0; r < 4; ++r) {
                int g2 = r0 + kb * 4 + r;
                if (g2 < n) dp[(size_t)g2 * 4 + (m & 3)] = e[r];
            }
        }
    }

    // main GEMM: 16 col-tiles x 2 MFMA
    #pragma unroll 4
    for (int ct = 0; ct < 16; ++ct) {
        f16x8 b0 = *(const f16x8*)(Wf + (ct * 64 + lane) * 8);
        f16x8 b1 = *(const f16x8*)(Wf + ((16 + ct) * 64 + lane) * 8);
        f32x4 d; d[0] = 0.f; d[1] = 0.f; d[2] = 0.f; d[3] = 0.f;
        d = __builtin_amdgcn_mfma_f32_16x16x32_f16(A0, b0, d, 0, 0, 0);
        d = __builtin_amdgcn_mfma_f32_16x16x32_f16(A1, b1, d, 0, 0, 0);
        int col = ct * 16 + m;
        #pragma unroll
        for (int r = 0; r < 4; ++r) {
            int g2 = r0 + kb * 4 + r;
            if (g2 < n) ft[(size_t)g2 * 256 + col] = (_Float16)d[r];
        }
    }
}

// Fused edge-softmax + aggregation + bias. One wave per dst node.
// First 16-edge chunk kept in registers across both passes (deg<=16 is ~97%).
__global__ __launch_bounds__(256) void k_agg(
        const int* __restrict__ rowptr, const int* __restrict__ csr_src,
        const float* __restrict__ el, const float* __restrict__ er,
        const __half* __restrict__ ft, const float* __restrict__ bsum,
        float* __restrict__ out, int n) {
    __shared__ float lds_ee[4][64];
    __shared__ int   lds_s[4][16];
    int wid  = (int)((blockIdx.x * blockDim.x + threadIdx.x) >> 6);
    int w    = (threadIdx.x >> 6) & 3;
    int lane = threadIdx.x & 63;
    if (wid >= n) return;
    int d = wid;
    int rbeg = rowptr[d], rend = rowptr[d + 1];
    float bs = bsum[lane];
    if (rend == rbeg) { out[(size_t)d * 64 + lane] = bs; return; }

    int ei = lane >> 2, hh = lane & 3;
    float erh = er[(size_t)d * 4 + hh];

    // pass 1: per-head max; chunk 0 cached in registers
    int s0 = -1; float x0 = 0.f;
    float m = -FINF;
    {
        int idx = rbeg + ei;
        if (idx < rend) {
            s0 = csr_src[idx];
            float x = el[(size_t)s0 * 4 + hh] + erh;
            x0 = x > 0.f ? x : NEG_SLOPE * x;
            m = x0;
        }
    }
    for (int base = rbeg + 16; base < rend; base += 16) {
        int idx = base + ei;
        if (idx < rend) {
            int s = csr_src[idx];
            float x = el[(size_t)s * 4 + hh] + erh;
            x = x > 0.f ? x : NEG_SLOPE * x;
            m = fmaxf(m, x);
        }
    }
    #pragma unroll
    for (int msk = 4; msk < 64; msk <<= 1) m = fmaxf(m, __shfl_xor(m, msk));

    // pass 2: chunk 0 from registers, rest re-gathered
    float dsum = 0.f;
    float4 acc = make_float4(0.f, 0.f, 0.f, 0.f);
    {
        float ee = 0.f;
        if (s0 >= 0) {
            ee = __expf(x0 - m);
            dsum += ee;
            if (hh == 0) lds_s[w][ei] = s0;
        }
        lds_ee[w][lane] = ee;
        int e16 = min(16, rend - rbeg);
        for (int i = 0; i < e16; ++i) {
            float4 ee4 = *(float4*)&lds_ee[w][i * 4];
            int s = lds_s[w][i];
            uint2 u = *(const uint2*)(ft + (size_t)s * 256 + (lane << 2));
            float2 fa = __half22float2(*(__half2*)&u.x);
            float2 fb = __half22float2(*(__half2*)&u.y);
            acc.x += ee4.x * fa.x; acc.y += ee4.y * fa.y;
            acc.z += ee4.z * fb.x; acc.w += ee4.w * fb.y;
        }
    }
    for (int base = rbeg + 16; base < rend; base += 16) {
        int idx = base + ei;
        int e16 = min(16, rend - base);
        float ee = 0.f;
        if (idx < rend) {
            int s = csr_src[idx];
            float x = el[(size_t)s * 4 + hh] + erh;
            x = x > 0.f ? x : NEG_SLOPE * x;
            ee = __expf(x - m);
            dsum += ee;
            if (hh == 0) lds_s[w][ei] = s;
        }
        lds_ee[w][lane] = ee;
        for (int i = 0; i < e16; ++i) {
            float4 ee4 = *(float4*)&lds_ee[w][i * 4];
            int s = lds_s[w][i];
            uint2 u = *(const uint2*)(ft + (size_t)s * 256 + (lane << 2));
            float2 fa = __half22float2(*(__half2*)&u.x);
            float2 fb = __half22float2(*(__half2*)&u.y);
            acc.x += ee4.x * fa.x; acc.y += ee4.y * fa.y;
            acc.z += ee4.z * fb.x; acc.w += ee4.w * fb.y;
        }
    }
    #pragma unroll
    for (int msk = 4; msk < 64; msk <<= 1) dsum += __shfl_xor(dsum, msk);
    float d0 = __shfl(dsum, 0), d1 = __shfl(dsum, 1);
    float d2 = __shfl(dsum, 2), d3 = __shfl(dsum, 3);
    out[(size_t)d * 64 + lane] = acc.x / d0 + acc.y / d1 + acc.z / d2 + acc.w / d3 + bs;
}

// ================= launcher =================

extern "C" void kernel_launch(void* const* d_in, const int* in_sizes, int n_in,
                              void* d_out, int out_size, void* d_ws, size_t ws_size,
                              hipStream_t stream) {
    const float* feat = (const float*)d_in[0];
    const float* W    = (const float*)d_in[1];
    const float* al   = (const float*)d_in[2];
    const float* ar   = (const float*)d_in[3];
    const float* bias = (const float*)d_in[4];
    const int*   src  = (const int*)d_in[5];
    const int*   dst  = (const int*)d_in[6];
    float* out = (float*)d_out;

    const int N = in_sizes[0] / 64;   // 50000
    const int E = in_sizes[5];        // 500000
    const int L = 4;

    // workspace carve (float units)
    float* ws = (float*)d_ws;
    _Float16* ft = (_Float16*)ws;                      // N*256 halves = N*128 floats
    float* hA   = ws + (size_t)N * 128;                // N*64
    float* hB   = hA + (size_t)N * 64;                 // N*64
    float* el   = hB + (size_t)N * 64;                 // N*4
    float* er   = el + (size_t)N * 4;                  // N*4
    float* WAB  = er + (size_t)N * 4;                  // 4*512
    float* bsum = WAB + 4 * 512;                       // 4*64
    _Float16* Wf   = (_Float16*)(bsum + 4 * 64);       // 4*16384 halves = 4*8192 f
    _Float16* WABf = (_Float16*)((float*)Wf + 4 * 8192); // 4*1024 halves = 4*512 f
    int* rowptr  = (int*)((float*)WABf + 4 * 512);     // N+1
    int* cursor  = rowptr + (N + 1);                   // N
    int* deg     = cursor + N;                         // N
    int* csr_src = deg + N;                            // E
    int* bsums   = csr_src + E;                        // 32
    int* boff    = bsums + 32;                         // 32

    const int NB = (N + SCB - 1) / SCB;                // 25

    // ---- prologue: CSR build + weight prep (once per call) ----
    hipMemsetAsync(deg, 0, (size_t)N * sizeof(int), stream);
    k_deg<<<(E + 255) / 256, 256, 0, stream>>>(dst, deg, E);
    k_scan1<<<NB, 256, 0, stream>>>(deg, bsums, N);
    k_scan2<<<1, 64, 0, stream>>>(bsums, boff, rowptr, NB, N);
    k_scan3<<<NB, 256, 0, stream>>>(deg, boff, rowptr, cursor, N);
    k_scatter<<<(E + 255) / 256, 256, 0, stream>>>(src, dst, cursor, csr_src, E);
    k_prep<<<(4 * 64 * 8 + 4 * 64 + 255) / 256, 256, 0, stream>>>(
        W, al, ar, bias, WAB, bsum);
    k_packW<<<(4 * 16384 + 255) / 256, 256, 0, stream>>>(W, Wf);
    k_packAB<<<(4 * 1024 + 255) / 256, 256, 0, stream>>>(WAB, WABf);

    // ---- layers ----
    const float* hin = feat;
    for (int l = 0; l < L; ++l) {
        float* hout = (l == L - 1) ? out : ((l & 1) ? hB : hA);
        k_gemm<<<(N + 63) / 64, 256, 0, stream>>>(
            hin, Wf + (size_t)l * 16384, WABf + (size_t)l * 1024,
            ft, el, er, N);
        k_agg<<<((size_t)N * 64 + 255) / 256, 256, 0, stream>>>(
            rowptr, csr_src, el, er, (const __half*)ft, bsum + (size_t)l * 64, hout, N);
        hin = hout;
    }
}